// Round 11
// baseline (488.916 us; speedup 1.0000x reference)
//
#include <hip/hip_runtime.h>

#define NN 100000
#define EE 1600000
#define C 256
#define OUTC 10
#define NG 64

#define BSH 7              // bucket = dst >> 7 (128-node buckets)
#define NBK 782            // ceil(NN/128) dst-buckets
#define CHUNK 2048         // edges per hist/scatter block
#define NBLK1 ((EE + CHUNK - 1) / CHUNK)
#define PADSLACK 1024      // per-bucket csrcol slack: 128*7 pad + 7 align < 1024

// agg_pool decomposition: 4 waves/block, each wave owns NODES_PER_GROUP nodes
#define NODES_PER_GROUP 8
#define NODES_PER_BLOCK 32      // 100000 = 32 * 3125 exactly
#define AGG_BLOCKS 3125
#define AGG_Q 782               // quarter split: 782,782,782,779

#define PRE_CNT_BLKS 391        // count blocks
#define PRE_W1_BLKS 256         // w1pack blocks

typedef __bf16 bf16x8 __attribute__((ext_vector_type(8)));
typedef float f32x4 __attribute__((ext_vector_type(4)));
typedef float f32x2 __attribute__((ext_vector_type(2)));

// channel permutation: PHYSICAL byte position p in a g row holds LOGICAL
// channel c = ((p&15)<<4) | (p>>4)  (transpose involution).
__device__ __forceinline__ int chan_logical(int p) {
    return ((p & 15) << 4) | (p >> 4);
}

// ---------------- bf16 helpers (RNE) ----------------
__device__ __forceinline__ ushort f2bf(float f) {
    unsigned u = __float_as_uint(f);
    return (ushort)((u + 0x7fffu + ((u >> 16) & 1u)) >> 16);
}
__device__ __forceinline__ bf16x8 as_bf16x8(uint4 v) {
    union { uint4 u; bf16x8 b; } c; c.u = v; return c.b;
}

// fp8 e4m3 decode/accumulate via HW converts
__device__ __forceinline__ void acc_fp8x4(float4& s, unsigned v) {
    f32x2 lo = __builtin_amdgcn_cvt_pk_f32_fp8(v, false);
    f32x2 hi = __builtin_amdgcn_cvt_pk_f32_fp8(v, true);
    s.x += lo[0]; s.y += lo[1]; s.z += hi[0]; s.w += hi[1];
}

// ---------------- fused pre-pass: bucket hist + graph count + W1 pack ----------
// blocks [0, NBLK1)                : LDS-staged bucket histogram of dst>>7
// blocks [NBLK1, NBLK1+391)        : per-graph node counts (batch histogram)
// blocks [NBLK1+391, +256)         : W1 -> bf16 fragment pack (+ zero g row NN)
__global__ __launch_bounds__(256) void pre_kernel(const int* __restrict__ ei,
                                                  int* __restrict__ bhist,
                                                  const int* __restrict__ batch,
                                                  float* __restrict__ cnt,
                                                  const float* __restrict__ W1,
                                                  ushort* __restrict__ w1f,
                                                  unsigned* __restrict__ gz) {
    __shared__ int h[NBK];
    const int bid = blockIdx.x;
    const int t = threadIdx.x;
    if (bid < NBLK1) {
        for (int i = t; i < NBK; i += 256) h[i] = 0;
        __syncthreads();
        const int base = bid * CHUNK;
        const int end = min(base + CHUNK, EE);
        for (int e = base + t; e < end; e += 256)
            atomicAdd(&h[ei[EE + e] >> BSH], 1);
        __syncthreads();
        for (int i = t; i < NBK; i += 256)
            if (h[i]) atomicAdd(&bhist[i], h[i]);
    } else if (bid < NBLK1 + PRE_CNT_BLKS) {
        if (t < NG) h[t] = 0;
        __syncthreads();
        int i = (bid - NBLK1) * 256 + t;
        if (i < NN) atomicAdd(&h[batch[i]], 1);
        __syncthreads();
        if (t < NG && h[t]) atomicAdd(&cnt[t], (float)h[t]);
    } else {
        int wb = bid - (NBLK1 + PRE_CNT_BLKS);
        int tt = wb * 256 + t;
        if (wb == 0 && t < 64) gz[t] = 0;   // sentinel g row NN = 0
        int k = tt >> 8, n = tt & 255;
        int kb = k >> 5, q = (k >> 3) & 3, j = k & 7;
        int nt = n >> 4, ln = (n & 15) + q * 16;
        w1f[(size_t)(((kb * 16 + nt) * 64) + ln) * 8 + j] = f2bf(W1[tt]);
    }
}

// ---------------- parallel exclusive scan of 782 bucket counts ----------------
__global__ __launch_bounds__(1024) void bucket_scan_kernel(const int* __restrict__ bhist,
                                                           int* __restrict__ bbase,
                                                           int* __restrict__ bcur) {
    __shared__ int sc[1024];
    const int t = threadIdx.x;
    int v = (t < NBK) ? bhist[t] : 0;
    sc[t] = v;
    __syncthreads();
    for (int off = 1; off < 1024; off <<= 1) {
        int tmp = (t >= off) ? sc[t - off] : 0;
        __syncthreads();
        sc[t] += tmp;
        __syncthreads();
    }
    int excl = sc[t] - v;
    if (t < NBK) { bbase[t] = excl; bcur[t] = excl; }
    if (t == NBK - 1) bbase[NBK] = sc[t];
}

// ---------------- scatter edges into bucket-major packed records ----------------
// record = (dst & 127) << 17 | src
__global__ __launch_bounds__(256) void bucket_scatter_kernel(const int* __restrict__ ei,
                                                             int* __restrict__ bcur,
                                                             unsigned* __restrict__ bmaj) {
    __shared__ int h[NBK];
    for (int t = threadIdx.x; t < NBK; t += 256) h[t] = 0;
    __syncthreads();
    const int base = blockIdx.x * CHUNK;
    const int end = min(base + CHUNK, EE);
    for (int e = base + threadIdx.x; e < end; e += 256)
        atomicAdd(&h[ei[EE + e] >> BSH], 1);
    __syncthreads();
    for (int t = threadIdx.x; t < NBK; t += 256) {
        int c = h[t];
        h[t] = c ? atomicAdd(&bcur[t], c) : 0;
    }
    __syncthreads();
    for (int e = base + threadIdx.x; e < end; e += 256) {
        int d = ei[EE + e];
        int s = ei[e];
        int b = d >> BSH;
        int p = atomicAdd(&h[b], 1);
        bmaj[p] = (unsigned)s | ((unsigned)(d & 127) << 17);
    }
}

// ---------------- per-bucket: degree, PADDED rowend, dinv, dense csrcol ----------
// 128-node buckets. Node lists = edges padded to mult of 8 with sentinel NN
// (zero g row); self-loop handled in agg directly. Region b starts at
// align8(bbase[b]) + b*PADSLACK (16B-aligned int4 loads).
__global__ __launch_bounds__(256) void bucket_csr_kernel(const unsigned* __restrict__ bmaj,
                                                         const int* __restrict__ bbase,
                                                         int* __restrict__ rowend,
                                                         float* __restrict__ dinv,
                                                         int* __restrict__ csrcol) {
    __shared__ int h[128];
    __shared__ int sc[128];
    __shared__ int cur[128];
    const int b = blockIdx.x;
    const int t = threadIdx.x;
    const int e0 = bbase[b], e1 = bbase[b + 1];
    const int region0 = ((e0 + 7) & ~7) + b * PADSLACK;   // 8-int aligned
    if (t < 128) h[t] = 0;
    __syncthreads();
    for (int e = e0 + t; e < e1; e += 256)
        atomicAdd(&h[bmaj[e] >> 17], 1);
    __syncthreads();
    int deg = 0, pd = 0, node = 0;
    if (t < 128) {
        deg = h[t];
        node = b * 128 + t;
        pd = (node < NN) ? ((deg + 7) & ~7) : 0;
        sc[t] = pd;
    }
    __syncthreads();
    for (int off = 1; off < 128; off <<= 1) {
        int tmp = (t >= off && t < 128) ? sc[t - off] : 0;
        __syncthreads();
        if (t < 128) sc[t] += tmp;
        __syncthreads();
    }
    if (t < 128) {
        int pstart = region0 + sc[t] - pd;
        if (node < NN) {
            rowend[node] = pstart + pd;        // PADDED end
            dinv[node] = rsqrtf((float)deg + 1.0f);
            for (int j = deg; j < pd; j++) csrcol[pstart + j] = NN;   // sentinels
        }
        cur[t] = pstart;
    }
    __syncthreads();
    for (int e = e0 + t; e < e1; e += 256) {
        unsigned v = bmaj[e];
        int p = atomicAdd(&cur[v >> 17], 1);
        csrcol[p] = (int)(v & 0x1FFFFu);
    }
}

// ---------------- g = fp8((x @ W1) * dinv[row]) — MFMA, LDS-free ----------------
// 1-deep A(x) prefetch: per K-step, issue the 16 B-loads FIRST, then the 4
// next-iteration x-loads, with sched_barrier fences pinning issue order.
// vmcnt is in-order, so the MFMA's wait on the (older) B-loads leaves the
// (newer) A-loads in flight across the MFMA block + next B-loads -> the ~900cy
// HBM latency of x is hidden under a full iteration. (R10 counters: 61us,
// MfmaUtil 7.5%, all pipes idle = serial load->wait->MFMA chains.)
// Epilogue stores CONTIGUOUS 16B per lane per row (transpose channel perm).
__global__ __launch_bounds__(256, 2) void gemm_mfma_kernel(const float* __restrict__ x,
                                                           const ushort* __restrict__ w1f,
                                                           const float* __restrict__ dinv,
                                                           uchar* __restrict__ g) {
    const int lane = threadIdx.x & 63;
    const int wid = threadIdx.x >> 6;
    const int wave = blockIdx.x * 4 + wid;
    const int r0 = wave * 32;
    if (r0 >= NN) return;
    const int mrow = lane & 15;
    const int q = lane >> 4;

    f32x4 acc[2][16];
    #pragma unroll
    for (int mt = 0; mt < 2; mt++)
        #pragma unroll
        for (int nt = 0; nt < 16; nt++)
            acc[mt][nt] = (f32x4){0.f, 0.f, 0.f, 0.f};

    const float* xp0 = x + (size_t)(r0 + mrow) * C + q * 8;
    const float* xp1 = xp0 + (size_t)16 * C;
    const ushort* bp = w1f + (size_t)lane * 8;

    // prologue: A(0)
    float4 a0lo = *(const float4*)(xp0);
    float4 a0hi = *(const float4*)(xp0 + 4);
    float4 a1lo = *(const float4*)(xp1);
    float4 a1hi = *(const float4*)(xp1 + 4);

    #pragma unroll 1
    for (int kb = 0; kb < 8; kb++) {
        // B loads first (oldest in vmcnt order)
        uint4 bbv[16];
        const ushort* bkb = bp + (size_t)kb * 16 * 512;
        #pragma unroll
        for (int nt = 0; nt < 16; nt++)
            bbv[nt] = *(const uint4*)(bkb + (size_t)nt * 512);
        __builtin_amdgcn_sched_barrier(0);

        // A prefetch for kb+1 (newest; stays outstanding across MFMAs).
        // Last iteration: clamped in-bounds address, values unused.
        const int ko2 = (kb == 7) ? 0 : (kb + 1) * 32;
        float4 n0lo = *(const float4*)(xp0 + ko2);
        float4 n0hi = *(const float4*)(xp0 + ko2 + 4);
        float4 n1lo = *(const float4*)(xp1 + ko2);
        float4 n1hi = *(const float4*)(xp1 + ko2 + 4);
        __builtin_amdgcn_sched_barrier(0);

        bf16x8 a0, a1;
        a0[0] = (__bf16)a0lo.x; a0[1] = (__bf16)a0lo.y;
        a0[2] = (__bf16)a0lo.z; a0[3] = (__bf16)a0lo.w;
        a0[4] = (__bf16)a0hi.x; a0[5] = (__bf16)a0hi.y;
        a0[6] = (__bf16)a0hi.z; a0[7] = (__bf16)a0hi.w;
        a1[0] = (__bf16)a1lo.x; a1[1] = (__bf16)a1lo.y;
        a1[2] = (__bf16)a1lo.z; a1[3] = (__bf16)a1lo.w;
        a1[4] = (__bf16)a1hi.x; a1[5] = (__bf16)a1hi.y;
        a1[6] = (__bf16)a1hi.z; a1[7] = (__bf16)a1hi.w;

        #pragma unroll
        for (int nt = 0; nt < 16; nt++) {
            bf16x8 bb = as_bf16x8(bbv[nt]);
            acc[0][nt] = __builtin_amdgcn_mfma_f32_16x16x32_bf16(a0, bb, acc[0][nt], 0, 0, 0);
            acc[1][nt] = __builtin_amdgcn_mfma_f32_16x16x32_bf16(a1, bb, acc[1][nt], 0, 0, 0);
        }

        a0lo = n0lo; a0hi = n0hi; a1lo = n1lo; a1hi = n1hi;
    }

    #pragma unroll
    for (int mt = 0; mt < 2; mt++) {
        #pragma unroll
        for (int r = 0; r < 4; r++) {
            int row = r0 + mt * 16 + q * 4 + r;
            float dv = dinv[row];
            uint4 dw;
            unsigned t0, t1, t2, t3;
            t0 = __builtin_amdgcn_cvt_pk_fp8_f32(acc[mt][0][r] * dv,  acc[mt][1][r] * dv,  0,  false);
            dw.x = __builtin_amdgcn_cvt_pk_fp8_f32(acc[mt][2][r] * dv,  acc[mt][3][r] * dv,  t0, true);
            t1 = __builtin_amdgcn_cvt_pk_fp8_f32(acc[mt][4][r] * dv,  acc[mt][5][r] * dv,  0,  false);
            dw.y = __builtin_amdgcn_cvt_pk_fp8_f32(acc[mt][6][r] * dv,  acc[mt][7][r] * dv,  t1, true);
            t2 = __builtin_amdgcn_cvt_pk_fp8_f32(acc[mt][8][r] * dv,  acc[mt][9][r] * dv,  0,  false);
            dw.z = __builtin_amdgcn_cvt_pk_fp8_f32(acc[mt][10][r] * dv, acc[mt][11][r] * dv, t2, true);
            t3 = __builtin_amdgcn_cvt_pk_fp8_f32(acc[mt][12][r] * dv, acc[mt][13][r] * dv, 0,  false);
            dw.w = __builtin_amdgcn_cvt_pk_fp8_f32(acc[mt][14][r] * dv, acc[mt][15][r] * dv, t3, true);
            *(uint4*)(g + (size_t)row * C + mrow * 16) = dw;
        }
    }
}

// ---------------- aggregate + relu + fused mean-pool (fp8, padded lists) --------
// R1-proven structure: full-row gather (64 lanes x 4B = 256B/record), separate
// self-loop load, int4 index loads. FOUR quarter dispatches (~33us top-5
// visibility floor). Bias read through inverse channel permutation.
__global__ __launch_bounds__(256) void agg_pool_kernel(const unsigned* __restrict__ g32,
                                                       const int* __restrict__ rowend,
                                                       const int* __restrict__ csrcol,
                                                       const int* __restrict__ bbase,
                                                       const float* __restrict__ dinv,
                                                       const float* __restrict__ b1,
                                                       const int* __restrict__ batch,
                                                       float* __restrict__ sums,
                                                       const int blk0) {
    const int lane = threadIdx.x & 63;
    const int wid = threadIdx.x >> 6;
    const int c4 = lane * 4;
    const int nodeA = (blockIdx.x + blk0) * NODES_PER_BLOCK + wid * NODES_PER_GROUP;
    float4 bv;
    bv.x = b1[chan_logical(c4 + 0)];
    bv.y = b1[chan_logical(c4 + 1)];
    bv.z = b1[chan_logical(c4 + 2)];
    bv.w = b1[chan_logical(c4 + 3)];
    const unsigned* gp = g32 + lane;

    int rprev;
    if ((nodeA & 127) == 0) {
        int b = nodeA >> BSH;
        rprev = ((bbase[b] + 7) & ~7) + b * PADSLACK;   // aligned bucket region start
    } else {
        rprev = rowend[nodeA - 1];
    }

    float4 pool = make_float4(0.f, 0.f, 0.f, 0.f);
    int curb = -1;
    #pragma unroll 1
    for (int i = nodeA; i < nodeA + NODES_PER_GROUP; i++) {
        int r1 = rowend[i];
        int r0 = rprev;
        rprev = r1;
        int bi = batch[i];
        if (bi != curb) {
            if (curb >= 0) {
                atomicAdd(&sums[curb * C + c4 + 0], pool.x);
                atomicAdd(&sums[curb * C + c4 + 1], pool.y);
                atomicAdd(&sums[curb * C + c4 + 2], pool.z);
                atomicAdd(&sums[curb * C + c4 + 3], pool.w);
            }
            curb = bi;
            pool = make_float4(0.f, 0.f, 0.f, 0.f);
        }
        float4 s = make_float4(0.f, 0.f, 0.f, 0.f);
        acc_fp8x4(s, gp[(size_t)i * 64]);               // self-loop term
        #pragma unroll 1
        for (int e = r0; e < r1; e += 8) {
            int4 iv0 = *(const int4*)(csrcol + e);       // 16B-aligned (e % 8 == 0)
            int4 iv1 = *(const int4*)(csrcol + e + 4);
            unsigned v0 = gp[(size_t)iv0.x * 64];
            unsigned v1 = gp[(size_t)iv0.y * 64];
            unsigned v2 = gp[(size_t)iv0.z * 64];
            unsigned v3 = gp[(size_t)iv0.w * 64];
            unsigned v4 = gp[(size_t)iv1.x * 64];
            unsigned v5 = gp[(size_t)iv1.y * 64];
            unsigned v6 = gp[(size_t)iv1.z * 64];
            unsigned v7 = gp[(size_t)iv1.w * 64];
            acc_fp8x4(s, v0); acc_fp8x4(s, v1); acc_fp8x4(s, v2); acc_fp8x4(s, v3);
            acc_fp8x4(s, v4); acc_fp8x4(s, v5); acc_fp8x4(s, v6); acc_fp8x4(s, v7);
        }
        float dv = dinv[i];
        pool.x += fmaxf(fmaf(dv, s.x, bv.x), 0.f);
        pool.y += fmaxf(fmaf(dv, s.y, bv.y), 0.f);
        pool.z += fmaxf(fmaf(dv, s.z, bv.z), 0.f);
        pool.w += fmaxf(fmaf(dv, s.w, bv.w), 0.f);
    }
    if (curb >= 0) {
        atomicAdd(&sums[curb * C + c4 + 0], pool.x);
        atomicAdd(&sums[curb * C + c4 + 1], pool.y);
        atomicAdd(&sums[curb * C + c4 + 2], pool.z);
        atomicAdd(&sums[curb * C + c4 + 3], pool.w);
    }
}

// ---------------- pooled = sums/cnt; out = pooled @ W2 + b2 ----------------
// sums/pooled in PHYSICAL (permuted) channel order; W2 indexed via inverse map.
__global__ __launch_bounds__(256) void final_kernel(const float* __restrict__ sums,
                                                    const float* __restrict__ cnt,
                                                    const float* __restrict__ W2,
                                                    const float* __restrict__ b2,
                                                    float* __restrict__ out) {
    __shared__ float p[C];
    int gi = blockIdx.x;
    float cdiv = fmaxf(cnt[gi], 1.0f);
    p[threadIdx.x] = sums[gi * C + threadIdx.x] / cdiv;
    __syncthreads();
    if (threadIdx.x < OUTC) {
        float acc = b2[threadIdx.x];
        for (int k = 0; k < C; k++)
            acc += p[k] * W2[chan_logical(k) * OUTC + threadIdx.x];
        out[gi * OUTC + threadIdx.x] = acc;
    }
}

extern "C" void kernel_launch(void* const* d_in, const int* in_sizes, int n_in,
                              void* d_out, int out_size, void* d_ws, size_t ws_size,
                              hipStream_t stream) {
    const float* x     = (const float*)d_in[0];
    const int*   ei    = (const int*)d_in[1];
    const int*   batch = (const int*)d_in[2];
    const float* W1    = (const float*)d_in[3];
    const float* b1    = (const float*)d_in[4];
    const float* W2    = (const float*)d_in[5];
    const float* b2    = (const float*)d_in[6];
    float* out = (float*)d_out;

    char* w = (char*)d_ws;
    size_t off = 0;
    auto carve = [&](size_t bytes) {
        void* p = w + off;
        off = (off + bytes + 255) & ~(size_t)255;
        return p;
    };
    uchar*    g        = (uchar*)   carve((size_t)(NN + 1) * C);  // fp8 + sentinel row
    int*      rowend   = (int*)     carve((size_t)NN * 4);
    float*    dinv     = (float*)   carve((size_t)NN * 4);
    int*      csrcol   = (int*)     carve((size_t)(EE + (size_t)NBK * PADSLACK + 128) * 4);
    unsigned* bmaj     = (unsigned*)carve((size_t)EE * 4);
    int*      bbase    = (int*)     carve((size_t)(NBK + 1) * 4);
    int*      bcur     = (int*)     carve((size_t)NBK * 4);
    ushort*   w1f      = (ushort*)  carve((size_t)C * C * 2);
    // contiguous zero-init region:
    int*      bhist    = (int*)     carve((size_t)NBK * 4);
    float*    sums     = (float*)   carve((size_t)NG * C * 4);
    float*    cnt      = (float*)   carve((size_t)NG * 4);
    size_t zero_bytes = (size_t)((char*)cnt + (size_t)NG * 4 - (char*)bhist);

    hipMemsetAsync(bhist, 0, zero_bytes, stream);

    pre_kernel<<<NBLK1 + PRE_CNT_BLKS + PRE_W1_BLKS, 256, 0, stream>>>(
        ei, bhist, batch, cnt, W1, w1f, (unsigned*)(g + (size_t)NN * C));
    bucket_scan_kernel<<<1, 1024, 0, stream>>>(bhist, bbase, bcur);
    bucket_scatter_kernel<<<NBLK1, 256, 0, stream>>>(ei, bcur, bmaj);
    bucket_csr_kernel<<<NBK, 256, 0, stream>>>(bmaj, bbase, rowend, dinv, csrcol);
    gemm_mfma_kernel<<<(NN / 32 + 3) / 4, 256, 0, stream>>>(x, w1f, dinv, g);
    agg_pool_kernel<<<AGG_Q, 256, 0, stream>>>(
        (const unsigned*)g, rowend, csrcol, bbase, dinv, b1, batch, sums, 0);
    agg_pool_kernel<<<AGG_Q, 256, 0, stream>>>(
        (const unsigned*)g, rowend, csrcol, bbase, dinv, b1, batch, sums, AGG_Q);
    agg_pool_kernel<<<AGG_Q, 256, 0, stream>>>(
        (const unsigned*)g, rowend, csrcol, bbase, dinv, b1, batch, sums, 2 * AGG_Q);
    agg_pool_kernel<<<AGG_BLOCKS - 3 * AGG_Q, 256, 0, stream>>>(
        (const unsigned*)g, rowend, csrcol, bbase, dinv, b1, batch, sums, 3 * AGG_Q);
    final_kernel<<<NG, 256, 0, stream>>>(sums, cnt, W2, b2, out);
}

// Round 12
// 389.471 us; speedup vs baseline: 1.2553x; 1.2553x over previous
//
#include <hip/hip_runtime.h>

#define NN 100000
#define EE 1600000
#define C 256
#define OUTC 10
#define NG 64

#define BSH 7              // bucket = dst >> 7 (128-node buckets)
#define NBK 782            // ceil(NN/128) dst-buckets
#define CHUNK 2048         // edges per hist/scatter block
#define NBLK1 ((EE + CHUNK - 1) / CHUNK)
#define PADSLACK 1024      // per-bucket csrcol slack: 128*7 pad + 7 align < 1024

// agg_pool decomposition: 4 waves/block, each wave owns NODES_PER_GROUP nodes
#define NODES_PER_GROUP 8
#define NODES_PER_BLOCK 32      // 100000 = 32 * 3125 exactly
#define AGG_BLOCKS 3125         // SINGLE dispatch (splits measured -50us, R11)

#define PRE_CNT_BLKS 391        // count blocks
#define PRE_W1_BLKS 256         // w1pack blocks

typedef __bf16 bf16x8 __attribute__((ext_vector_type(8)));
typedef float f32x4 __attribute__((ext_vector_type(4)));
typedef float f32x2 __attribute__((ext_vector_type(2)));

// channel permutation: PHYSICAL byte position p in a g row holds LOGICAL
// channel c = ((p&15)<<4) | (p>>4)  (transpose involution).
__device__ __forceinline__ int chan_logical(int p) {
    return ((p & 15) << 4) | (p >> 4);
}

// ---------------- bf16 helpers (RNE) ----------------
__device__ __forceinline__ ushort f2bf(float f) {
    unsigned u = __float_as_uint(f);
    return (ushort)((u + 0x7fffu + ((u >> 16) & 1u)) >> 16);
}
__device__ __forceinline__ bf16x8 as_bf16x8(uint4 v) {
    union { uint4 u; bf16x8 b; } c; c.u = v; return c.b;
}

// fp8 e4m3 decode/accumulate via HW converts
__device__ __forceinline__ void acc_fp8x4(float4& s, unsigned v) {
    f32x2 lo = __builtin_amdgcn_cvt_pk_f32_fp8(v, false);
    f32x2 hi = __builtin_amdgcn_cvt_pk_f32_fp8(v, true);
    s.x += lo[0]; s.y += lo[1]; s.z += hi[0]; s.w += hi[1];
}

// ---------------- fused pre-pass: bucket hist + graph count + W1 pack ----------
// blocks [0, NBLK1)                : LDS-staged bucket histogram of dst>>7
// blocks [NBLK1, NBLK1+391)        : per-graph node counts (batch histogram)
// blocks [NBLK1+391, +256)         : W1 -> bf16 fragment pack (+ zero g row NN)
__global__ __launch_bounds__(256) void pre_kernel(const int* __restrict__ ei,
                                                  int* __restrict__ bhist,
                                                  const int* __restrict__ batch,
                                                  float* __restrict__ cnt,
                                                  const float* __restrict__ W1,
                                                  ushort* __restrict__ w1f,
                                                  unsigned* __restrict__ gz) {
    __shared__ int h[NBK];
    const int bid = blockIdx.x;
    const int t = threadIdx.x;
    if (bid < NBLK1) {
        for (int i = t; i < NBK; i += 256) h[i] = 0;
        __syncthreads();
        const int base = bid * CHUNK;
        const int end = min(base + CHUNK, EE);
        for (int e = base + t; e < end; e += 256)
            atomicAdd(&h[ei[EE + e] >> BSH], 1);
        __syncthreads();
        for (int i = t; i < NBK; i += 256)
            if (h[i]) atomicAdd(&bhist[i], h[i]);
    } else if (bid < NBLK1 + PRE_CNT_BLKS) {
        if (t < NG) h[t] = 0;
        __syncthreads();
        int i = (bid - NBLK1) * 256 + t;
        if (i < NN) atomicAdd(&h[batch[i]], 1);
        __syncthreads();
        if (t < NG && h[t]) atomicAdd(&cnt[t], (float)h[t]);
    } else {
        int wb = bid - (NBLK1 + PRE_CNT_BLKS);
        int tt = wb * 256 + t;
        if (wb == 0 && t < 64) gz[t] = 0;   // sentinel g row NN = 0
        int k = tt >> 8, n = tt & 255;
        int kb = k >> 5, q = (k >> 3) & 3, j = k & 7;
        int nt = n >> 4, ln = (n & 15) + q * 16;
        w1f[(size_t)(((kb * 16 + nt) * 64) + ln) * 8 + j] = f2bf(W1[tt]);
    }
}

// ---------------- parallel exclusive scan of 782 bucket counts ----------------
__global__ __launch_bounds__(1024) void bucket_scan_kernel(const int* __restrict__ bhist,
                                                           int* __restrict__ bbase,
                                                           int* __restrict__ bcur) {
    __shared__ int sc[1024];
    const int t = threadIdx.x;
    int v = (t < NBK) ? bhist[t] : 0;
    sc[t] = v;
    __syncthreads();
    for (int off = 1; off < 1024; off <<= 1) {
        int tmp = (t >= off) ? sc[t - off] : 0;
        __syncthreads();
        sc[t] += tmp;
        __syncthreads();
    }
    int excl = sc[t] - v;
    if (t < NBK) { bbase[t] = excl; bcur[t] = excl; }
    if (t == NBK - 1) bbase[NBK] = sc[t];
}

// ---------------- scatter edges into bucket-major packed records ----------------
// record = (dst & 127) << 17 | src
__global__ __launch_bounds__(256) void bucket_scatter_kernel(const int* __restrict__ ei,
                                                             int* __restrict__ bcur,
                                                             unsigned* __restrict__ bmaj) {
    __shared__ int h[NBK];
    for (int t = threadIdx.x; t < NBK; t += 256) h[t] = 0;
    __syncthreads();
    const int base = blockIdx.x * CHUNK;
    const int end = min(base + CHUNK, EE);
    for (int e = base + threadIdx.x; e < end; e += 256)
        atomicAdd(&h[ei[EE + e] >> BSH], 1);
    __syncthreads();
    for (int t = threadIdx.x; t < NBK; t += 256) {
        int c = h[t];
        h[t] = c ? atomicAdd(&bcur[t], c) : 0;
    }
    __syncthreads();
    for (int e = base + threadIdx.x; e < end; e += 256) {
        int d = ei[EE + e];
        int s = ei[e];
        int b = d >> BSH;
        int p = atomicAdd(&h[b], 1);
        bmaj[p] = (unsigned)s | ((unsigned)(d & 127) << 17);
    }
}

// ---------------- per-bucket: degree, PADDED rowend, dinv, dense csrcol ----------
// 128-node buckets. Node lists = edges padded to mult of 8 with sentinel NN
// (zero g row); self-loop handled in agg directly. Region b starts at
// align8(bbase[b]) + b*PADSLACK (16B-aligned int4 loads).
__global__ __launch_bounds__(256) void bucket_csr_kernel(const unsigned* __restrict__ bmaj,
                                                         const int* __restrict__ bbase,
                                                         int* __restrict__ rowend,
                                                         float* __restrict__ dinv,
                                                         int* __restrict__ csrcol) {
    __shared__ int h[128];
    __shared__ int sc[128];
    __shared__ int cur[128];
    const int b = blockIdx.x;
    const int t = threadIdx.x;
    const int e0 = bbase[b], e1 = bbase[b + 1];
    const int region0 = ((e0 + 7) & ~7) + b * PADSLACK;   // 8-int aligned
    if (t < 128) h[t] = 0;
    __syncthreads();
    for (int e = e0 + t; e < e1; e += 256)
        atomicAdd(&h[bmaj[e] >> 17], 1);
    __syncthreads();
    int deg = 0, pd = 0, node = 0;
    if (t < 128) {
        deg = h[t];
        node = b * 128 + t;
        pd = (node < NN) ? ((deg + 7) & ~7) : 0;
        sc[t] = pd;
    }
    __syncthreads();
    for (int off = 1; off < 128; off <<= 1) {
        int tmp = (t >= off && t < 128) ? sc[t - off] : 0;
        __syncthreads();
        if (t < 128) sc[t] += tmp;
        __syncthreads();
    }
    if (t < 128) {
        int pstart = region0 + sc[t] - pd;
        if (node < NN) {
            rowend[node] = pstart + pd;        // PADDED end
            dinv[node] = rsqrtf((float)deg + 1.0f);
            for (int j = deg; j < pd; j++) csrcol[pstart + j] = NN;   // sentinels
        }
        cur[t] = pstart;
    }
    __syncthreads();
    for (int e = e0 + t; e < e1; e += 256) {
        unsigned v = bmaj[e];
        int p = atomicAdd(&cur[v >> 17], 1);
        csrcol[p] = (int)(v & 0x1FFFFu);
    }
}

// ---------------- g = fp8((x @ W1) * dinv[row]) — MFMA + LDS-staged B ----------
// Per K-step the block cooperatively stages the CONTIGUOUS 16KB w1f kb-slice
// into LDS (each of 4 waves was re-reading the same slice from L2: 400MB
// aggregate, serial load->wait->MFMA chains, MfmaUtil 7.5%). B now comes from
// pipelined ds_read_b128; x(kb+1) is prefetched under the MFMA phase.
// All waves participate in barriers (inactive waves use clamped addresses).
// Epilogue stores CONTIGUOUS 16B per lane per row (transpose channel perm).
__global__ __launch_bounds__(256, 2) void gemm_mfma_kernel(const float* __restrict__ x,
                                                           const ushort* __restrict__ w1f,
                                                           const float* __restrict__ dinv,
                                                           uchar* __restrict__ g) {
    __shared__ ushort bsl[16 * 64 * 8];    // 16 KB: one kb-slice of w1f
    const int t = threadIdx.x;
    const int lane = t & 63;
    const int wid = t >> 6;
    const int wave = blockIdx.x * 4 + wid;
    const int r0 = wave * 32;
    const bool active = (r0 < NN);
    const int rbase = active ? r0 : 0;     // clamped for idle tail waves
    const int mrow = lane & 15;
    const int q = lane >> 4;

    f32x4 acc[2][16];
    #pragma unroll
    for (int mt = 0; mt < 2; mt++)
        #pragma unroll
        for (int nt = 0; nt < 16; nt++)
            acc[mt][nt] = (f32x4){0.f, 0.f, 0.f, 0.f};

    const float* xp0 = x + (size_t)(rbase + mrow) * C + q * 8;
    const float* xp1 = xp0 + (size_t)16 * C;

    // prologue: x(0)
    float4 a0lo = *(const float4*)(xp0);
    float4 a0hi = *(const float4*)(xp0 + 4);
    float4 a1lo = *(const float4*)(xp1);
    float4 a1hi = *(const float4*)(xp1 + 4);

    #pragma unroll 1
    for (int kb = 0; kb < 8; kb++) {
        // cooperative stage: 16KB slice = 1024 uint4, 4 per thread
        const uint4* src = (const uint4*)(w1f + (size_t)kb * 8192);
        uint4* dst = (uint4*)bsl;
        #pragma unroll
        for (int rr = 0; rr < 4; rr++)
            dst[rr * 256 + t] = src[rr * 256 + t];
        __syncthreads();                       // stage visible to all waves

        bf16x8 a0, a1;
        a0[0] = (__bf16)a0lo.x; a0[1] = (__bf16)a0lo.y;
        a0[2] = (__bf16)a0lo.z; a0[3] = (__bf16)a0lo.w;
        a0[4] = (__bf16)a0hi.x; a0[5] = (__bf16)a0hi.y;
        a0[6] = (__bf16)a0hi.z; a0[7] = (__bf16)a0hi.w;
        a1[0] = (__bf16)a1lo.x; a1[1] = (__bf16)a1lo.y;
        a1[2] = (__bf16)a1lo.z; a1[3] = (__bf16)a1lo.w;
        a1[4] = (__bf16)a1hi.x; a1[5] = (__bf16)a1hi.y;
        a1[6] = (__bf16)a1hi.z; a1[7] = (__bf16)a1hi.w;

        // x prefetch for kb+1 overlaps the MFMA phase below
        if (kb < 7) {
            const int ko2 = (kb + 1) * 32;
            a0lo = *(const float4*)(xp0 + ko2);
            a0hi = *(const float4*)(xp0 + ko2 + 4);
            a1lo = *(const float4*)(xp1 + ko2);
            a1hi = *(const float4*)(xp1 + ko2 + 4);
        }

        const uint4* bl = (const uint4*)bsl;
        #pragma unroll
        for (int nt = 0; nt < 16; nt++) {
            bf16x8 bb = as_bf16x8(bl[nt * 64 + lane]);   // ds_read_b128
            acc[0][nt] = __builtin_amdgcn_mfma_f32_16x16x32_bf16(a0, bb, acc[0][nt], 0, 0, 0);
            acc[1][nt] = __builtin_amdgcn_mfma_f32_16x16x32_bf16(a1, bb, acc[1][nt], 0, 0, 0);
        }
        __syncthreads();                       // protect LDS before next stage
    }

    if (active) {
        #pragma unroll
        for (int mt = 0; mt < 2; mt++) {
            #pragma unroll
            for (int r = 0; r < 4; r++) {
                int row = r0 + mt * 16 + q * 4 + r;
                float dv = dinv[row];
                uint4 dw;
                unsigned t0, t1, t2, t3;
                t0 = __builtin_amdgcn_cvt_pk_fp8_f32(acc[mt][0][r] * dv,  acc[mt][1][r] * dv,  0,  false);
                dw.x = __builtin_amdgcn_cvt_pk_fp8_f32(acc[mt][2][r] * dv,  acc[mt][3][r] * dv,  t0, true);
                t1 = __builtin_amdgcn_cvt_pk_fp8_f32(acc[mt][4][r] * dv,  acc[mt][5][r] * dv,  0,  false);
                dw.y = __builtin_amdgcn_cvt_pk_fp8_f32(acc[mt][6][r] * dv,  acc[mt][7][r] * dv,  t1, true);
                t2 = __builtin_amdgcn_cvt_pk_fp8_f32(acc[mt][8][r] * dv,  acc[mt][9][r] * dv,  0,  false);
                dw.z = __builtin_amdgcn_cvt_pk_fp8_f32(acc[mt][10][r] * dv, acc[mt][11][r] * dv, t2, true);
                t3 = __builtin_amdgcn_cvt_pk_fp8_f32(acc[mt][12][r] * dv, acc[mt][13][r] * dv, 0,  false);
                dw.w = __builtin_amdgcn_cvt_pk_fp8_f32(acc[mt][14][r] * dv, acc[mt][15][r] * dv, t3, true);
                *(uint4*)(g + (size_t)row * C + mrow * 16) = dw;
            }
        }
    }
}

// ---------------- aggregate + relu + fused mean-pool (fp8, padded lists) --------
// R1-proven structure: full-row gather (64 lanes x 4B = 256B/record), separate
// self-loop load, int4 index loads. SINGLE dispatch (splits cost ~50us, R11).
// Bias read through inverse channel permutation.
__global__ __launch_bounds__(256) void agg_pool_kernel(const unsigned* __restrict__ g32,
                                                       const int* __restrict__ rowend,
                                                       const int* __restrict__ csrcol,
                                                       const int* __restrict__ bbase,
                                                       const float* __restrict__ dinv,
                                                       const float* __restrict__ b1,
                                                       const int* __restrict__ batch,
                                                       float* __restrict__ sums) {
    const int lane = threadIdx.x & 63;
    const int wid = threadIdx.x >> 6;
    const int c4 = lane * 4;
    const int nodeA = blockIdx.x * NODES_PER_BLOCK + wid * NODES_PER_GROUP;
    float4 bv;
    bv.x = b1[chan_logical(c4 + 0)];
    bv.y = b1[chan_logical(c4 + 1)];
    bv.z = b1[chan_logical(c4 + 2)];
    bv.w = b1[chan_logical(c4 + 3)];
    const unsigned* gp = g32 + lane;

    int rprev;
    if ((nodeA & 127) == 0) {
        int b = nodeA >> BSH;
        rprev = ((bbase[b] + 7) & ~7) + b * PADSLACK;   // aligned bucket region start
    } else {
        rprev = rowend[nodeA - 1];
    }

    float4 pool = make_float4(0.f, 0.f, 0.f, 0.f);
    int curb = -1;
    #pragma unroll 1
    for (int i = nodeA; i < nodeA + NODES_PER_GROUP; i++) {
        int r1 = rowend[i];
        int r0 = rprev;
        rprev = r1;
        int bi = batch[i];
        if (bi != curb) {
            if (curb >= 0) {
                atomicAdd(&sums[curb * C + c4 + 0], pool.x);
                atomicAdd(&sums[curb * C + c4 + 1], pool.y);
                atomicAdd(&sums[curb * C + c4 + 2], pool.z);
                atomicAdd(&sums[curb * C + c4 + 3], pool.w);
            }
            curb = bi;
            pool = make_float4(0.f, 0.f, 0.f, 0.f);
        }
        float4 s = make_float4(0.f, 0.f, 0.f, 0.f);
        acc_fp8x4(s, gp[(size_t)i * 64]);               // self-loop term
        #pragma unroll 1
        for (int e = r0; e < r1; e += 8) {
            int4 iv0 = *(const int4*)(csrcol + e);       // 16B-aligned (e % 8 == 0)
            int4 iv1 = *(const int4*)(csrcol + e + 4);
            unsigned v0 = gp[(size_t)iv0.x * 64];
            unsigned v1 = gp[(size_t)iv0.y * 64];
            unsigned v2 = gp[(size_t)iv0.z * 64];
            unsigned v3 = gp[(size_t)iv0.w * 64];
            unsigned v4 = gp[(size_t)iv1.x * 64];
            unsigned v5 = gp[(size_t)iv1.y * 64];
            unsigned v6 = gp[(size_t)iv1.z * 64];
            unsigned v7 = gp[(size_t)iv1.w * 64];
            acc_fp8x4(s, v0); acc_fp8x4(s, v1); acc_fp8x4(s, v2); acc_fp8x4(s, v3);
            acc_fp8x4(s, v4); acc_fp8x4(s, v5); acc_fp8x4(s, v6); acc_fp8x4(s, v7);
        }
        float dv = dinv[i];
        pool.x += fmaxf(fmaf(dv, s.x, bv.x), 0.f);
        pool.y += fmaxf(fmaf(dv, s.y, bv.y), 0.f);
        pool.z += fmaxf(fmaf(dv, s.z, bv.z), 0.f);
        pool.w += fmaxf(fmaf(dv, s.w, bv.w), 0.f);
    }
    if (curb >= 0) {
        atomicAdd(&sums[curb * C + c4 + 0], pool.x);
        atomicAdd(&sums[curb * C + c4 + 1], pool.y);
        atomicAdd(&sums[curb * C + c4 + 2], pool.z);
        atomicAdd(&sums[curb * C + c4 + 3], pool.w);
    }
}

// ---------------- pooled = sums/cnt; out = pooled @ W2 + b2 ----------------
// sums/pooled in PHYSICAL (permuted) channel order; W2 indexed via inverse map.
__global__ __launch_bounds__(256) void final_kernel(const float* __restrict__ sums,
                                                    const float* __restrict__ cnt,
                                                    const float* __restrict__ W2,
                                                    const float* __restrict__ b2,
                                                    float* __restrict__ out) {
    __shared__ float p[C];
    int gi = blockIdx.x;
    float cdiv = fmaxf(cnt[gi], 1.0f);
    p[threadIdx.x] = sums[gi * C + threadIdx.x] / cdiv;
    __syncthreads();
    if (threadIdx.x < OUTC) {
        float acc = b2[threadIdx.x];
        for (int k = 0; k < C; k++)
            acc += p[k] * W2[chan_logical(k) * OUTC + threadIdx.x];
        out[gi * OUTC + threadIdx.x] = acc;
    }
}

extern "C" void kernel_launch(void* const* d_in, const int* in_sizes, int n_in,
                              void* d_out, int out_size, void* d_ws, size_t ws_size,
                              hipStream_t stream) {
    const float* x     = (const float*)d_in[0];
    const int*   ei    = (const int*)d_in[1];
    const int*   batch = (const int*)d_in[2];
    const float* W1    = (const float*)d_in[3];
    const float* b1    = (const float*)d_in[4];
    const float* W2    = (const float*)d_in[5];
    const float* b2    = (const float*)d_in[6];
    float* out = (float*)d_out;

    char* w = (char*)d_ws;
    size_t off = 0;
    auto carve = [&](size_t bytes) {
        void* p = w + off;
        off = (off + bytes + 255) & ~(size_t)255;
        return p;
    };
    uchar*    g        = (uchar*)   carve((size_t)(NN + 1) * C);  // fp8 + sentinel row
    int*      rowend   = (int*)     carve((size_t)NN * 4);
    float*    dinv     = (float*)   carve((size_t)NN * 4);
    int*      csrcol   = (int*)     carve((size_t)(EE + (size_t)NBK * PADSLACK + 128) * 4);
    unsigned* bmaj     = (unsigned*)carve((size_t)EE * 4);
    int*      bbase    = (int*)     carve((size_t)(NBK + 1) * 4);
    int*      bcur     = (int*)     carve((size_t)NBK * 4);
    ushort*   w1f      = (ushort*)  carve((size_t)C * C * 2);
    // contiguous zero-init region:
    int*      bhist    = (int*)     carve((size_t)NBK * 4);
    float*    sums     = (float*)   carve((size_t)NG * C * 4);
    float*    cnt      = (float*)   carve((size_t)NG * 4);
    size_t zero_bytes = (size_t)((char*)cnt + (size_t)NG * 4 - (char*)bhist);

    hipMemsetAsync(bhist, 0, zero_bytes, stream);

    pre_kernel<<<NBLK1 + PRE_CNT_BLKS + PRE_W1_BLKS, 256, 0, stream>>>(
        ei, bhist, batch, cnt, W1, w1f, (unsigned*)(g + (size_t)NN * C));
    bucket_scan_kernel<<<1, 1024, 0, stream>>>(bhist, bbase, bcur);
    bucket_scatter_kernel<<<NBLK1, 256, 0, stream>>>(ei, bcur, bmaj);
    bucket_csr_kernel<<<NBK, 256, 0, stream>>>(bmaj, bbase, rowend, dinv, csrcol);
    gemm_mfma_kernel<<<(NN / 32 + 3) / 4, 256, 0, stream>>>(x, w1f, dinv, g);
    agg_pool_kernel<<<AGG_BLOCKS, 256, 0, stream>>>(
        (const unsigned*)g, rowend, csrcol, bbase, dinv, b1, batch, sums);
    final_kernel<<<NG, 256, 0, stream>>>(sums, cnt, W2, b2, out);
}